// Round 7
// baseline (499.564 us; speedup 1.0000x reference)
//
#include <hip/hip_runtime.h>

// ---------------------------------------------------------------------------
// 2-layer GCN: out = log_softmax( A_hat( relu( A_hat(X W1)+b1 ) W2 ) + b2 )
// A_hat = D^-1/2 (A+I) D^-1/2, deg = indegree(dst)+1 (self-loop).
// R5: ZERO global atomics; LDS histogram binning -> dense copy-out.
// R6: record-parallel build_rows; agg csr loads predicated on lane<n_e.
// R7: GEMM1 BK=64 + reg double-buffer; build_rows LDS-window + dense copy.
// R9/R10 FAILED accuracy (absmax 0.09375 = 3 bf16 quanta vs thr 0.091875),
//     error bit-identical across both -> NOT P2 precision; the agg summation
//     REORDER (serial -> 4-way strided groups) flips boundary-adjacent H1
//     bf16 roundings (quantum 0.03125), tripling final error. Lesson: the
//     serial edge order is part of the verified numerics.
// R12: aggs reverted to the exact R3 serial per-lane order (known 0.03125
//     pass). Kept: R7 GEMM1/build_rows, f32 P2 epilogue + f32 softmax agg
//     input (strictly closer to ref than R3; 2B ushort loads -> 4B float).
// ---------------------------------------------------------------------------

#define NN 100000
#define EE 1600000
#define F_IN 512
#define HID 128
#define CLS 64
#define CAP 64            // padded CSR row capacity (== wavesize)
#define NBUCK 391         // ceil(NN/256) buckets of 256 nodes
#define EPB 4096          // edges per build block
#define EPT 16            // edges per thread (EPB/256)
#define NBLK 391          // ceil(EE/EPB) build blocks

typedef __bf16 v8bf __attribute__((ext_vector_type(8)));
typedef float v4f __attribute__((ext_vector_type(4)));
typedef unsigned int uint;
typedef unsigned short ushort;

__device__ __forceinline__ float bf_lo(uint u) { return __uint_as_float(u << 16); }
__device__ __forceinline__ float bf_hi(uint u) { return __uint_as_float(u & 0xffff0000u); }

// ------------------------- small prep kernels ------------------------------

__global__ void cvt_weights(const float* __restrict__ W1, const float* __restrict__ W2,
                            __bf16* __restrict__ W1t, __bf16* __restrict__ W2t) {
    int i = blockIdx.x * 256 + threadIdx.x;
    if (i < F_IN * HID) { int k = i / HID, n = i % HID; W1t[(size_t)n * F_IN + k] = (__bf16)W1[i]; }
    if (i < HID * CLS)  { int k = i / CLS,  n = i % CLS; W2t[(size_t)n * HID + k] = (__bf16)W2[i]; }
}

// ------------- fused: LDS edge binning (pass 1a) + GEMM1 (X @ W1) ----------
template<int BM, int BN, int BK, int K>
__global__ __launch_bounds__(256) void fused_bin_gemm1(
        const float* __restrict__ X, const __bf16* __restrict__ Bt,
        __bf16* __restrict__ Out, int M,
        const int* __restrict__ src, const int* __restrict__ dst,
        int* __restrict__ boff, int* __restrict__ bcnt, uint* __restrict__ bbuf) {
    constexpr int SA = BK + 8;
    constexpr int SB = BK + 8;
    constexpr int LDS_BYTES = (BM * SA + BN * SB) * 2;   // 36864 for 128/128/64
    static_assert(EPB * 4 + (NBUCK + 1) * 8 + 49 * 4 <= LDS_BYTES, "build LDS fits");
    __shared__ __align__(16) char smem[LDS_BYTES];
    const int tid = threadIdx.x;

    if (blockIdx.x < NBLK) {
        // ---------------- binning path (LDS only) ----------------
        uint* lrec  = (uint*)smem;                        // EPB records
        int*  lhist = (int*)(smem + EPB * 4);             // NBUCK+1 (last = invalid)
        int*  loff  = lhist + (NBUCK + 1);
        int*  asum  = loff + (NBUCK + 1);                 // 49 group sums
        const int blk = blockIdx.x;
        const int base = blk * EPB;
        for (int i = tid; i < NBUCK + 1; i += 256) lhist[i] = 0;
        __syncthreads();
        uint rec[EPT]; int bk[EPT], pos[EPT];
        #pragma unroll
        for (int j = 0; j < EPT; ++j) {
            int idx = base + tid + j * 256;               // coalesced
            bool ok = idx < EE;
            int ii = ok ? idx : 0;
            unsigned ud = (unsigned)dst[ii]; if (ud >= NN) ud = 0;
            unsigned us = (unsigned)src[ii]; if (us >= NN) us = 0;
            rec[j] = (us << 8) | (ud & 255u);
            bk[j] = ok ? (int)(ud >> 8) : NBUCK;
            pos[j] = atomicAdd(&lhist[bk[j]], 1);         // LDS atomic
        }
        __syncthreads();
        // exclusive scan of lhist[0..391] (49 groups of 8)
        if (tid < 49) {
            int s = 0;
            #pragma unroll
            for (int k = 0; k < 8; ++k) s += lhist[tid * 8 + k];
            asum[tid] = s;
        }
        __syncthreads();
        if (tid == 0) {
            int run = 0;
            for (int g = 0; g < 49; ++g) { int t = asum[g]; asum[g] = run; run += t; }
        }
        __syncthreads();
        if (tid < 49) {
            int run = asum[tid];
            #pragma unroll
            for (int k = 0; k < 8; ++k) { loff[tid * 8 + k] = run; run += lhist[tid * 8 + k]; }
        }
        __syncthreads();
        #pragma unroll
        for (int j = 0; j < EPT; ++j)
            lrec[loff[bk[j]] + pos[j]] = rec[j];          // LDS scatter
        __syncthreads();
        for (int i = tid; i < EPB; i += 256)              // dense 16KB copy-out
            bbuf[base + i] = lrec[i];
        for (int q = tid; q < NBUCK; q += 256) {
            boff[q * NBLK + blk] = base + loff[q];
            bcnt[q * NBLK + blk] = lhist[q];
        }
        return;
    }

    // ---------------- GEMM path (reg double-buffered staging) ----------------
    __bf16* As = (__bf16*)smem;                // BM*SA
    __bf16* Bs = As + BM * SA;                 // BN*SB
    const int m0 = (blockIdx.x - NBLK) * BM;
    constexpr int WM = BM / 2, WN = BN / 2;
    constexpr int MT = WM / 16, NT = WN / 16;
    const int w = tid >> 6, lane = tid & 63;
    const int wm = w & 1, wn = w >> 1;
    const int lr = lane & 15;
    const int lq = lane >> 4;

    constexpr int C8 = BK / 8;                 // 8-float chunks per row (8)
    constexpr int APT = BM * C8 / 256;         // A chunks per thread (4)
    constexpr int BPT = BN * C8 / 256;         // B chunks per thread (4)

    v4f acc[MT][NT] = {};
    float4 ga[APT][2];
    uint4  gb[BPT];

    auto prefetch = [&](int k0) {
        #pragma unroll
        for (int c = 0; c < APT; ++c) {
            int sgi = tid + c * 256;
            int row = sgi / C8, c8 = sgi % C8;
            int gr = m0 + row; if (gr >= M) gr = M - 1;
            const float* g = X + (size_t)gr * K + k0 + c8 * 8;
            ga[c][0] = *(const float4*)g;
            ga[c][1] = *(const float4*)(g + 4);
        }
        #pragma unroll
        for (int c = 0; c < BPT; ++c) {
            int sgi = tid + c * 256;
            int n = sgi / C8, c8 = sgi % C8;
            gb[c] = *(const uint4*)(Bt + (size_t)n * K + k0 + c8 * 8);
        }
    };
    auto commit = [&]() {
        #pragma unroll
        for (int c = 0; c < APT; ++c) {
            int sgi = tid + c * 256;
            int row = sgi / C8, c8 = sgi % C8;
            __bf16 b[8];
            b[0] = (__bf16)ga[c][0].x; b[1] = (__bf16)ga[c][0].y;
            b[2] = (__bf16)ga[c][0].z; b[3] = (__bf16)ga[c][0].w;
            b[4] = (__bf16)ga[c][1].x; b[5] = (__bf16)ga[c][1].y;
            b[6] = (__bf16)ga[c][1].z; b[7] = (__bf16)ga[c][1].w;
            *(uint4*)&As[row * SA + c8 * 8] = *(uint4*)b;
        }
        #pragma unroll
        for (int c = 0; c < BPT; ++c) {
            int sgi = tid + c * 256;
            int n = sgi / C8, c8 = sgi % C8;
            *(uint4*)&Bs[n * SB + c8 * 8] = gb[c];
        }
    };

    prefetch(0);
    for (int k0 = 0; k0 < K; k0 += BK) {
        commit();                               // regs -> LDS (cvt A)
        __syncthreads();                        // tile ready
        if (k0 + BK < K) prefetch(k0 + BK);     // overlap HBM latency w/ MFMA
        #pragma unroll
        for (int kk = 0; kk < BK; kk += 32) {
            v8bf a[MT], bfr[NT];
            #pragma unroll
            for (int i = 0; i < MT; ++i)
                a[i] = *(const v8bf*)&As[(wm * WM + i * 16 + lr) * SA + kk + lq * 8];
            #pragma unroll
            for (int j = 0; j < NT; ++j)
                bfr[j] = *(const v8bf*)&Bs[(wn * WN + j * 16 + lr) * SB + kk + lq * 8];
            #pragma unroll
            for (int i = 0; i < MT; ++i)
                #pragma unroll
                for (int j = 0; j < NT; ++j)
                    acc[i][j] = __builtin_amdgcn_mfma_f32_16x16x32_bf16(a[i], bfr[j], acc[i][j], 0, 0, 0);
        }
        __syncthreads();                        // reads done before next commit
    }
    #pragma unroll
    for (int i = 0; i < MT; ++i)
        #pragma unroll
        for (int j = 0; j < NT; ++j)
            #pragma unroll
            for (int r = 0; r < 4; ++r) {
                int row = m0 + wm * WM + i * 16 + lq * 4 + r;
                if (row < M) {
                    int col = wn * WN + j * 16 + lr;
                    Out[(size_t)row * BN + col] = (__bf16)acc[i][j][r];
                }
            }
}

// ---------------- pass 1b: per-bucket padded-row construction --------------
__global__ __launch_bounds__(256) void build_rows(const uint* __restrict__ bbuf,
                                                  const int* __restrict__ boff,
                                                  const int* __restrict__ bcnt,
                                                  int* __restrict__ cnt,
                                                  float* __restrict__ inv,
                                                  int* __restrict__ csr_pad) {
    __shared__ int lcnt[256];
    __shared__ int soff[NBLK];
    __shared__ int sc[392];      // counts, padded to 49*8
    __shared__ int spre[392];    // exclusive prefix
    __shared__ int gsum[49];
    __shared__ __align__(16) int win[256 * CAP];   // 64 KB padded-row window
    const int q = blockIdx.x, tid = threadIdx.x;
    lcnt[tid] = 0;
    for (int b = tid; b < 392; b += 256) sc[b] = (b < NBLK) ? bcnt[q * NBLK + b] : 0;
    for (int b = tid; b < NBLK; b += 256) soff[b] = boff[q * NBLK + b];
    __syncthreads();
    if (tid < 49) {
        int s = 0;
        #pragma unroll
        for (int k = 0; k < 8; ++k) s += sc[tid * 8 + k];
        gsum[tid] = s;
    }
    __syncthreads();
    if (tid == 0) {
        int run = 0;
        for (int g = 0; g < 49; ++g) { int t = gsum[g]; gsum[g] = run; run += t; }
    }
    __syncthreads();
    if (tid < 49) {
        int run = gsum[tid];
        #pragma unroll
        for (int k = 0; k < 8; ++k) { spre[tid * 8 + k] = run; run += sc[tid * 8 + k]; }
    }
    __syncthreads();
    const int total = spre[391];                          // sc[391]==0 pad
    const int v0 = q * 256;
    for (int r = tid; r < total; r += 256) {
        // largest lo in [0,390] with spre[lo] <= r
        int lo = 0, hi = 390;
        while (hi > lo) { int mid = (lo + hi + 1) >> 1; if (spre[mid] <= r) lo = mid; else hi = mid - 1; }
        uint rec = bbuf[soff[lo] + (r - spre[lo])];
        int vl = (int)(rec & 255u);
        int s  = (int)(rec >> 8);
        int p = atomicAdd(&lcnt[vl], 1);                  // LDS atomic
        if (p < CAP) win[vl * CAP + p] = s;               // LDS scatter
    }
    __syncthreads();
    {   // dense coalesced copy-out (slots >= cnt are garbage; aggs predicate)
        const int4* s4 = (const int4*)win;
        int4* d4 = (int4*)(csr_pad + (size_t)v0 * CAP);
        for (int i = tid; i < 256 * CAP / 4; i += 256) d4[i] = s4[i];
    }
    int v = v0 + tid;
    if (v < NN) {
        cnt[v] = lcnt[tid];
        inv[v] = rsqrtf((float)(lcnt[tid] + 1));
    }
}

// --------------------- GEMM2 (bf16 in, f32 out) ----------------------------
// f32 epilogue -- full logit precision for the softmax agg.
template<int BM, int BN, int BK, int K>
__global__ __launch_bounds__(256) void gemm_bt(const __bf16* __restrict__ A,
                                               const __bf16* __restrict__ Bt,
                                               float* __restrict__ Out, int M) {
    constexpr int SA = BK + 8;
    constexpr int SB = BK + 8;
    __shared__ __align__(16) __bf16 As[BM * SA];
    __shared__ __align__(16) __bf16 Bs[BN * SB];
    const int tid = threadIdx.x;
    const int m0 = blockIdx.x * BM;
    constexpr int WM = BM / 2, WN = BN / 2;
    constexpr int MT = WM / 16, NT = WN / 16;
    const int w = tid >> 6, lane = tid & 63;
    const int wm = w & 1, wn = w >> 1;
    const int lr = lane & 15;
    const int lq = lane >> 4;

    v4f acc[MT][NT] = {};

    for (int k0 = 0; k0 < K; k0 += BK) {
        {
            constexpr int CH = BM * (BK / 8);
            for (int s = tid; s < CH; s += 256) {
                int row = s / (BK / 8), c8 = s % (BK / 8);
                int gr = m0 + row; if (gr >= M) gr = M - 1;
                uint4 val = *(const uint4*)(A + (size_t)gr * K + k0 + c8 * 8);
                *(uint4*)&As[row * SA + c8 * 8] = val;
            }
        }
        {
            constexpr int CH = BN * (BK / 8);
            for (int s = tid; s < CH; s += 256) {
                int n = s / (BK / 8), c8 = s % (BK / 8);
                uint4 val = *(const uint4*)(Bt + (size_t)n * K + k0 + c8 * 8);
                *(uint4*)&Bs[n * SB + c8 * 8] = val;
            }
        }
        __syncthreads();
        #pragma unroll
        for (int kk = 0; kk < BK; kk += 32) {
            v8bf a[MT], bfr[NT];
            #pragma unroll
            for (int i = 0; i < MT; ++i)
                a[i] = *(const v8bf*)&As[(wm * WM + i * 16 + lr) * SA + kk + lq * 8];
            #pragma unroll
            for (int j = 0; j < NT; ++j)
                bfr[j] = *(const v8bf*)&Bs[(wn * WN + j * 16 + lr) * SB + kk + lq * 8];
            #pragma unroll
            for (int i = 0; i < MT; ++i)
                #pragma unroll
                for (int j = 0; j < NT; ++j)
                    acc[i][j] = __builtin_amdgcn_mfma_f32_16x16x32_bf16(a[i], bfr[j], acc[i][j], 0, 0, 0);
        }
        __syncthreads();
    }
    #pragma unroll
    for (int i = 0; i < MT; ++i)
        #pragma unroll
        for (int j = 0; j < NT; ++j)
            #pragma unroll
            for (int r = 0; r < 4; ++r) {
                int row = m0 + wm * WM + i * 16 + lq * 4 + r;
                if (row < M) {
                    int col = wn * WN + j * 16 + lr;
                    Out[(size_t)row * BN + col] = acc[i][j][r];
                }
            }
}

// --------------------------- aggregation kernels ---------------------------
// R12: EXACT R3 serial per-lane structure (verified absmax 0.03125).
// Wave-per-node: lane l reads csr row element l (CAP==64), coefs computed
// per-lane, broadcast via __shfl. Serial edge order j=0..n_e-1.

// HID=128: lane handles features {2l, 2l+1} as packed bf16x2 (uint).
__global__ __launch_bounds__(256) void agg_relu_w(const uint* __restrict__ Hin,
                                                  const float* __restrict__ inv,
                                                  const int* __restrict__ cnt,
                                                  const int* __restrict__ csr_pad,
                                                  const float* __restrict__ bias,
                                                  uint* __restrict__ Hout) {
    const int wid = threadIdx.x >> 6, lane = threadIdx.x & 63;
    const int v = blockIdx.x * 4 + wid;
    if (v >= NN) return;
    const float isv = inv[v];
    const int n_e = min(cnt[v], CAP);
    int sidx = 0;
    if (lane < n_e) sidx = csr_pad[(size_t)v * CAP + lane];   // predicated fetch
    float c = inv[sidx] * isv;
    uint u = Hin[(size_t)v * 64 + lane];
    float ax = bf_lo(u) * isv * isv;
    float ay = bf_hi(u) * isv * isv;
    int j = 0;
    for (; j + 3 < n_e; j += 4) {
        int s0 = __shfl(sidx, j), s1 = __shfl(sidx, j + 1);
        int s2 = __shfl(sidx, j + 2), s3 = __shfl(sidx, j + 3);
        float c0 = __shfl(c, j), c1 = __shfl(c, j + 1);
        float c2 = __shfl(c, j + 2), c3 = __shfl(c, j + 3);
        uint h0 = Hin[(size_t)s0 * 64 + lane];
        uint h1 = Hin[(size_t)s1 * 64 + lane];
        uint h2 = Hin[(size_t)s2 * 64 + lane];
        uint h3 = Hin[(size_t)s3 * 64 + lane];
        ax += c0 * bf_lo(h0); ay += c0 * bf_hi(h0);
        ax += c1 * bf_lo(h1); ay += c1 * bf_hi(h1);
        ax += c2 * bf_lo(h2); ay += c2 * bf_hi(h2);
        ax += c3 * bf_lo(h3); ay += c3 * bf_hi(h3);
    }
    for (; j < n_e; ++j) {
        int s0 = __shfl(sidx, j);
        float c0 = __shfl(c, j);
        uint h0 = Hin[(size_t)s0 * 64 + lane];
        ax += c0 * bf_lo(h0); ay += c0 * bf_hi(h0);
    }
    float ox = fmaxf(ax + bias[2 * lane], 0.f);
    float oy = fmaxf(ay + bias[2 * lane + 1], 0.f);
    __bf16 blo = (__bf16)ox, bhi = (__bf16)oy;
    uint res = (uint)*(ushort*)&blo | ((uint)*(ushort*)&bhi << 16);
    Hout[(size_t)v * 64 + lane] = res;
}

// CLS=64: lane == class. Serial edge order; f32 logit rows (4B loads, was
// 2B ushort in R3 -- strictly more accurate and slightly wider).
__global__ __launch_bounds__(256) void agg_softmax_w(const float* __restrict__ Hin,
                                                     const float* __restrict__ inv,
                                                     const int* __restrict__ cnt,
                                                     const int* __restrict__ csr_pad,
                                                     const float* __restrict__ bias,
                                                     float* __restrict__ out) {
    const int wid = threadIdx.x >> 6, lane = threadIdx.x & 63;
    const int v = blockIdx.x * 4 + wid;
    if (v >= NN) return;
    const float isv = inv[v];
    const int n_e = min(cnt[v], CAP);
    int sidx = 0;
    if (lane < n_e) sidx = csr_pad[(size_t)v * CAP + lane];   // predicated fetch
    float c = inv[sidx] * isv;
    float acc = Hin[(size_t)v * 64 + lane] * isv * isv;
    int j = 0;
    for (; j + 3 < n_e; j += 4) {
        int s0 = __shfl(sidx, j), s1 = __shfl(sidx, j + 1);
        int s2 = __shfl(sidx, j + 2), s3 = __shfl(sidx, j + 3);
        float c0 = __shfl(c, j), c1 = __shfl(c, j + 1);
        float c2 = __shfl(c, j + 2), c3 = __shfl(c, j + 3);
        float h0 = Hin[(size_t)s0 * 64 + lane];
        float h1 = Hin[(size_t)s1 * 64 + lane];
        float h2 = Hin[(size_t)s2 * 64 + lane];
        float h3 = Hin[(size_t)s3 * 64 + lane];
        acc += c0 * h0;
        acc += c1 * h1;
        acc += c2 * h2;
        acc += c3 * h3;
    }
    for (; j < n_e; ++j) {
        int s0 = __shfl(sidx, j);
        float c0 = __shfl(c, j);
        float h0 = Hin[(size_t)s0 * 64 + lane];
        acc += c0 * h0;
    }
    float o = acc + bias[lane];
    float m = o;
    #pragma unroll
    for (int off = 32; off >= 1; off >>= 1) m = fmaxf(m, __shfl_xor(m, off, 64));
    float e = __expf(o - m);
    float s = e;
    #pragma unroll
    for (int off = 32; off >= 1; off >>= 1) s += __shfl_xor(s, off, 64);
    out[(size_t)v * CLS + lane] = (o - m) - __logf(s);
}

// ------------------------------- launcher ----------------------------------

extern "C" void kernel_launch(void* const* d_in, const int* in_sizes, int n_in,
                              void* d_out, int out_size, void* d_ws, size_t ws_size,
                              hipStream_t stream) {
    const float* x   = (const float*)d_in[0];
    const int*   src = (const int*)d_in[1];
    const int*   dst = (const int*)d_in[2];
    const float* W1  = (const float*)d_in[3];
    const float* b1  = (const float*)d_in[4];
    const float* W2  = (const float*)d_in[5];
    const float* b2  = (const float*)d_in[6];
    float* out = (float*)d_out;

    char* p = (char*)d_ws;
    size_t off = 0;
    auto alloc = [&](size_t bytes) {
        off = (off + 255) & ~(size_t)255;
        char* r = p + off;
        off += bytes;
        return r;
    };
    int*    cnt     = (int*)alloc(NN * 4);
    float*  inv     = (float*)alloc(NN * 4);
    int*    boff    = (int*)alloc((size_t)NBUCK * NBLK * 4);        // 0.6 MB
    int*    bcnt    = (int*)alloc((size_t)NBUCK * NBLK * 4);        // 0.6 MB
    uint*   bbuf    = (uint*)alloc((size_t)NBLK * EPB * 4);         // 6.4 MB
    int*    csr_pad = (int*)alloc((size_t)(NN + 256) * CAP * 4);    // 25.7 MB (+slack for dense copy)
    __bf16* W1t     = (__bf16*)alloc((size_t)F_IN * HID * 2);
    __bf16* W2t     = (__bf16*)alloc((size_t)HID * CLS * 2);
    __bf16* P1b     = (__bf16*)alloc((size_t)NN * HID * 2);
    __bf16* H1b     = (__bf16*)alloc((size_t)NN * HID * 2);
    float*  P2f     = (float*)alloc((size_t)NN * CLS * 4);          // 25.6 MB f32 logits

    cvt_weights<<<(F_IN * HID + 255) / 256, 256, 0, stream>>>(W1, W2, W1t, W2t);

    // pass1a binning (391 blocks) + GEMM1 X@W1 (782 blocks), fused
    const int MB1 = (NN + 127) / 128;    // 782
    fused_bin_gemm1<128, HID, 64, F_IN><<<NBLK + MB1, 256, 0, stream>>>(
        x, W1t, P1b, NN, src, dst, boff, bcnt, bbuf);

    build_rows<<<NBUCK, 256, 0, stream>>>(bbuf, boff, bcnt, cnt, inv, csr_pad);

    agg_relu_w<<<(NN + 3) / 4, 256, 0, stream>>>((const uint*)P1b, inv, cnt, csr_pad, b1, (uint*)H1b);

    gemm_bt<128, CLS, 128, HID><<<MB1, 256, 0, stream>>>(H1b, W2t, P2f, NN);

    agg_softmax_w<<<(NN + 3) / 4, 256, 0, stream>>>(P2f, inv, cnt, csr_pad, b2, out);
}

// Round 9
// 476.742 us; speedup vs baseline: 1.0479x; 1.0479x over previous
//
#include <hip/hip_runtime.h>

// ---------------------------------------------------------------------------
// 2-layer GCN: out = log_softmax( A_hat( relu( A_hat(X W1)+b1 ) W2 ) + b2 )
// A_hat = D^-1/2 (A+I) D^-1/2, deg = indegree(dst)+1 (self-loop).
// R5: ZERO global atomics; LDS histogram binning -> dense copy-out.
// R6: record-parallel build_rows; agg csr loads predicated on lane<n_e.
// R7: build_rows LDS-window + dense copy.
// R9/R10 FAILED accuracy: agg summation REORDER flips boundary-adjacent bf16
//     roundings. Lesson: serial edge order is part of the verified numerics.
// R12: aggs = exact R3 serial order (0.03125 pass). f32 P2 measured +9.3us
//     vs R3 bf16 P2 -- reverted here (R3 numerics verified 0.03125).
// R13: GEMM1 path rewritten with global_load_lds(16B) staging (m97 pattern):
//     f32 A-tile staged DIRECTLY to LDS (no reg staging, no commit-drain
//     stall), f32->bf16 cvt moved to fragment build (bit-identical rounding
//     + MFMA order => P1b bit-identical). Linear LDS + XOR swizzle
//     ((row&7)<<4) on both pre-swizzled global source and ds_read addr
//     (both-sides-or-neither rule) -> 16-way bank conflict eliminated.
//     R1 profile: fused 121.5us @ MfmaUtil 4%/HBM 16% = latency bind;
//     reg-prefetch (R7) couldn't cover ~900cyc HBM latency with ~160cyc
//     of MFMA. Predicted: fused -> 55-70us, hbm_gbps >= 3 TB/s.
// R14: identical resubmit of R13 -- bench infra failed (container
//     acquisition transient, 4th occurrence; prior resubmits ran clean).
// ---------------------------------------------------------------------------

#define NN 100000
#define EE 1600000
#define F_IN 512
#define HID 128
#define CLS 64
#define CAP 64            // padded CSR row capacity (== wavesize)
#define NBUCK 391         // ceil(NN/256) buckets of 256 nodes
#define EPB 4096          // edges per build block
#define EPT 16            // edges per thread (EPB/256)
#define NBLK 391          // ceil(EE/EPB) build blocks

typedef __bf16 v8bf __attribute__((ext_vector_type(8)));
typedef float v4f __attribute__((ext_vector_type(4)));
typedef unsigned int uint;
typedef unsigned short ushort;

__device__ __forceinline__ float bf_lo(uint u) { return __uint_as_float(u << 16); }
__device__ __forceinline__ float bf_hi(uint u) { return __uint_as_float(u & 0xffff0000u); }

// async global->LDS, 16B per lane; dest = wave-uniform base + lane*16
__device__ __forceinline__ void load_lds16(const void* g, void* l) {
    __builtin_amdgcn_global_load_lds(
        (__attribute__((address_space(1))) void*)(void*)g,
        (__attribute__((address_space(3))) void*)l,
        16, 0, 0);
}

// ------------------------- small prep kernels ------------------------------

__global__ void cvt_weights(const float* __restrict__ W1, const float* __restrict__ W2,
                            __bf16* __restrict__ W1t, __bf16* __restrict__ W2t) {
    int i = blockIdx.x * 256 + threadIdx.x;
    if (i < F_IN * HID) { int k = i / HID, n = i % HID; W1t[(size_t)n * F_IN + k] = (__bf16)W1[i]; }
    if (i < HID * CLS)  { int k = i / CLS,  n = i % CLS; W2t[(size_t)n * HID + k] = (__bf16)W2[i]; }
}

// ------------- fused: LDS edge binning (pass 1a) + GEMM1 (X @ W1) ----------
// build blocks [0,NBLK): 4096 edges -> LDS hist/scan/scatter -> dense copy.
// gemm blocks [NBLK,...): 128x128 tile, BK=64, global_load_lds staging.
// LDS union: GEMM = 32KB f32 A-tile + 16KB bf16 B-tile = 48KB (3 blocks/CU);
// binning needs 19716 B.
template<int BM, int BN, int BK, int K>
__global__ __launch_bounds__(256) void fused_bin_gemm1(
        const float* __restrict__ X, const __bf16* __restrict__ Bt,
        __bf16* __restrict__ Out, int M,
        const int* __restrict__ src, const int* __restrict__ dst,
        int* __restrict__ boff, int* __restrict__ bcnt, uint* __restrict__ bbuf) {
    static_assert(BM == 128 && BN == 128 && BK == 64, "geometry fixed");
    constexpr int LDS_BYTES = BM * BK * 4 + BN * BK * 2;   // 49152
    static_assert(EPB * 4 + (NBUCK + 1) * 8 + 49 * 4 <= LDS_BYTES, "build LDS fits");
    __shared__ __align__(16) char smem[LDS_BYTES];
    const int tid = threadIdx.x;

    if (blockIdx.x < NBLK) {
        // ---------------- binning path (LDS only) ----------------
        uint* lrec  = (uint*)smem;                        // EPB records
        int*  lhist = (int*)(smem + EPB * 4);             // NBUCK+1 (last = invalid)
        int*  loff  = lhist + (NBUCK + 1);
        int*  asum  = loff + (NBUCK + 1);                 // 49 group sums
        const int blk = blockIdx.x;
        const int base = blk * EPB;
        for (int i = tid; i < NBUCK + 1; i += 256) lhist[i] = 0;
        __syncthreads();
        uint rec[EPT]; int bk[EPT], pos[EPT];
        #pragma unroll
        for (int j = 0; j < EPT; ++j) {
            int idx = base + tid + j * 256;               // coalesced
            bool ok = idx < EE;
            int ii = ok ? idx : 0;
            unsigned ud = (unsigned)dst[ii]; if (ud >= NN) ud = 0;
            unsigned us = (unsigned)src[ii]; if (us >= NN) us = 0;
            rec[j] = (us << 8) | (ud & 255u);
            bk[j] = ok ? (int)(ud >> 8) : NBUCK;
            pos[j] = atomicAdd(&lhist[bk[j]], 1);         // LDS atomic
        }
        __syncthreads();
        // exclusive scan of lhist[0..391] (49 groups of 8)
        if (tid < 49) {
            int s = 0;
            #pragma unroll
            for (int k = 0; k < 8; ++k) s += lhist[tid * 8 + k];
            asum[tid] = s;
        }
        __syncthreads();
        if (tid == 0) {
            int run = 0;
            for (int g = 0; g < 49; ++g) { int t = asum[g]; asum[g] = run; run += t; }
        }
        __syncthreads();
        if (tid < 49) {
            int run = asum[tid];
            #pragma unroll
            for (int k = 0; k < 8; ++k) { loff[tid * 8 + k] = run; run += lhist[tid * 8 + k]; }
        }
        __syncthreads();
        #pragma unroll
        for (int j = 0; j < EPT; ++j)
            lrec[loff[bk[j]] + pos[j]] = rec[j];          // LDS scatter
        __syncthreads();
        for (int i = tid; i < EPB; i += 256)              // dense 16KB copy-out
            bbuf[base + i] = lrec[i];
        for (int q = tid; q < NBUCK; q += 256) {
            boff[q * NBLK + blk] = base + loff[q];
            bcnt[q * NBLK + blk] = lhist[q];
        }
        return;
    }

    // ------------- GEMM path (global_load_lds + swizzled linear LDS) -------
    // A: f32 [128][64], LDS byte = r*256 + ((c*4) ^ ((r&7)<<4))
    // B: bf16 [128][64], LDS byte = n*128 + ((c*2) ^ ((n&7)<<4))
    // cvt f32->bf16 at fragment build == old stage-time cvt (bit-identical).
    char* Af = smem;                           // 32 KB
    char* Bb = smem + BM * BK * 4;             // 16 KB
    const int m0 = (blockIdx.x - NBLK) * BM;
    const int w = tid >> 6, lane = tid & 63;
    const int wm = w & 1, wn = w >> 1;
    const int lr = lane & 15;
    const int lq = lane >> 4;

    v4f acc[4][4] = {};

    for (int k0 = 0; k0 < K; k0 += BK) {
        // ---- stage A: 32 x 1KB chunks, 8 per wave (pre-swizzled source) ----
        #pragma unroll
        for (int i = 0; i < 8; ++i) {
            int chunk = w * 8 + i;
            int r  = chunk * 4 + (lane >> 4);
            int cb = ((lane & 15) * 16) ^ ((r & 7) << 4);   // swizzled col-bytes
            int gr = m0 + r; if (gr >= M) gr = M - 1;
            load_lds16(X + (size_t)gr * K + k0 + (cb >> 2), Af + chunk * 1024);
        }
        // ---- stage B: 16 x 1KB chunks, 4 per wave ----
        #pragma unroll
        for (int i = 0; i < 4; ++i) {
            int chunk = w * 4 + i;
            int n  = chunk * 8 + (lane >> 3);
            int cb = ((lane & 7) * 16) ^ ((n & 7) << 4);
            load_lds16(Bt + (size_t)n * K + k0 + (cb >> 1), Bb + chunk * 1024);
        }
        __syncthreads();                       // drains vmcnt; tile ready
        #pragma unroll
        for (int kk = 0; kk < BK; kk += 32) {
            v8bf a[4], bfr[4];
            #pragma unroll
            for (int i = 0; i < 4; ++i) {
                int r = wm * 64 + i * 16 + lr;
                int base = r * 256 + (((kk + lq * 8) * 4) ^ ((r & 7) << 4));
                float4 f0 = *(const float4*)(Af + base);
                float4 f1 = *(const float4*)(Af + (base ^ 16));  // col+16 == ^16 (col mult of 32)
                v8bf av;
                av[0] = (__bf16)f0.x; av[1] = (__bf16)f0.y;
                av[2] = (__bf16)f0.z; av[3] = (__bf16)f0.w;
                av[4] = (__bf16)f1.x; av[5] = (__bf16)f1.y;
                av[6] = (__bf16)f1.z; av[7] = (__bf16)f1.w;
                a[i] = av;
            }
            #pragma unroll
            for (int j = 0; j < 4; ++j) {
                int n = wn * 64 + j * 16 + lr;
                int boff = n * 128 + (((kk + lq * 8) * 2) ^ ((n & 7) << 4));
                bfr[j] = *(const v8bf*)(Bb + boff);
            }
            #pragma unroll
            for (int i = 0; i < 4; ++i)
                #pragma unroll
                for (int j = 0; j < 4; ++j)
                    acc[i][j] = __builtin_amdgcn_mfma_f32_16x16x32_bf16(a[i], bfr[j], acc[i][j], 0, 0, 0);
        }
        __syncthreads();                       // reads done before next stage
    }
    #pragma unroll
    for (int i = 0; i < 4; ++i)
        #pragma unroll
        for (int j = 0; j < 4; ++j)
            #pragma unroll
            for (int r = 0; r < 4; ++r) {
                int row = m0 + wm * 64 + i * 16 + lq * 4 + r;
                if (row < M) {
                    int col = wn * 64 + j * 16 + lr;
                    Out[(size_t)row * BN + col] = (__bf16)acc[i][j][r];
                }
            }
}

// ---------------- pass 1b: per-bucket padded-row construction --------------
__global__ __launch_bounds__(256) void build_rows(const uint* __restrict__ bbuf,
                                                  const int* __restrict__ boff,
                                                  const int* __restrict__ bcnt,
                                                  int* __restrict__ cnt,
                                                  float* __restrict__ inv,
                                                  int* __restrict__ csr_pad) {
    __shared__ int lcnt[256];
    __shared__ int soff[NBLK];
    __shared__ int sc[392];      // counts, padded to 49*8
    __shared__ int spre[392];    // exclusive prefix
    __shared__ int gsum[49];
    __shared__ __align__(16) int win[256 * CAP];   // 64 KB padded-row window
    const int q = blockIdx.x, tid = threadIdx.x;
    lcnt[tid] = 0;
    for (int b = tid; b < 392; b += 256) sc[b] = (b < NBLK) ? bcnt[q * NBLK + b] : 0;
    for (int b = tid; b < NBLK; b += 256) soff[b] = boff[q * NBLK + b];
    __syncthreads();
    if (tid < 49) {
        int s = 0;
        #pragma unroll
        for (int k = 0; k < 8; ++k) s += sc[tid * 8 + k];
        gsum[tid] = s;
    }
    __syncthreads();
    if (tid == 0) {
        int run = 0;
        for (int g = 0; g < 49; ++g) { int t = gsum[g]; gsum[g] = run; run += t; }
    }
    __syncthreads();
    if (tid < 49) {
        int run = gsum[tid];
        #pragma unroll
        for (int k = 0; k < 8; ++k) { spre[tid * 8 + k] = run; run += sc[tid * 8 + k]; }
    }
    __syncthreads();
    const int total = spre[391];                          // sc[391]==0 pad
    const int v0 = q * 256;
    for (int r = tid; r < total; r += 256) {
        // largest lo in [0,390] with spre[lo] <= r
        int lo = 0, hi = 390;
        while (hi > lo) { int mid = (lo + hi + 1) >> 1; if (spre[mid] <= r) lo = mid; else hi = mid - 1; }
        uint rec = bbuf[soff[lo] + (r - spre[lo])];
        int vl = (int)(rec & 255u);
        int s  = (int)(rec >> 8);
        int p = atomicAdd(&lcnt[vl], 1);                  // LDS atomic
        if (p < CAP) win[vl * CAP + p] = s;               // LDS scatter
    }
    __syncthreads();
    {   // dense coalesced copy-out (slots >= cnt are garbage; aggs predicate)
        const int4* s4 = (const int4*)win;
        int4* d4 = (int4*)(csr_pad + (size_t)v0 * CAP);
        for (int i = tid; i < 256 * CAP / 4; i += 256) d4[i] = s4[i];
    }
    int v = v0 + tid;
    if (v < NN) {
        cnt[v] = lcnt[tid];
        inv[v] = rsqrtf((float)(lcnt[tid] + 1));
    }
}

// ------------------------------ GEMM2 (bf16 in/out) ------------------------
// R13: bf16 epilogue restored (R3-verified numerics; f32 cost +9.3us).
template<int BM, int BN, int BK, int K>
__global__ __launch_bounds__(256) void gemm_bt(const __bf16* __restrict__ A,
                                               const __bf16* __restrict__ Bt,
                                               __bf16* __restrict__ Out, int M) {
    constexpr int SA = BK + 8;
    constexpr int SB = BK + 8;
    __shared__ __align__(16) __bf16 As[BM * SA];
    __shared__ __align__(16) __bf16 Bs[BN * SB];
    const int tid = threadIdx.x;
    const int m0 = blockIdx.x * BM;
    constexpr int WM = BM / 2, WN = BN / 2;
    constexpr int MT = WM / 16, NT = WN / 16;
    const int w = tid >> 6, lane = tid & 63;
    const int wm = w & 1, wn = w >> 1;
    const int lr = lane & 15;
    const int lq = lane >> 4;

    v4f acc[MT][NT] = {};

    for (int k0 = 0; k0 < K; k0 += BK) {
        {
            constexpr int CH = BM * (BK / 8);
            for (int s = tid; s < CH; s += 256) {
                int row = s / (BK / 8), c8 = s % (BK / 8);
                int gr = m0 + row; if (gr >= M) gr = M - 1;
                uint4 val = *(const uint4*)(A + (size_t)gr * K + k0 + c8 * 8);
                *(uint4*)&As[row * SA + c8 * 8] = val;
            }
        }
        {
            constexpr int CH = BN * (BK / 8);
            for (int s = tid; s < CH; s += 256) {
                int n = s / (BK / 8), c8 = s % (BK / 8);
                uint4 val = *(const uint4*)(Bt + (size_t)n * K + k0 + c8 * 8);
                *(uint4*)&Bs[n * SB + c8 * 8] = val;
            }
        }
        __syncthreads();
        #pragma unroll
        for (int kk = 0; kk < BK; kk += 32) {
            v8bf a[MT], bfr[NT];
            #pragma unroll
            for (int i = 0; i < MT; ++i)
                a[i] = *(const v8bf*)&As[(wm * WM + i * 16 + lr) * SA + kk + lq * 8];
            #pragma unroll
            for (int j = 0; j < NT; ++j)
                bfr[j] = *(const v8bf*)&Bs[(wn * WN + j * 16 + lr) * SB + kk + lq * 8];
            #pragma unroll
            for (int i = 0; i < MT; ++i)
                #pragma unroll
                for (int j = 0; j < NT; ++j)
                    acc[i][j] = __builtin_amdgcn_mfma_f32_16x16x32_bf16(a[i], bfr[j], acc[i][j], 0, 0, 0);
        }
        __syncthreads();
    }
    #pragma unroll
    for (int i = 0; i < MT; ++i)
        #pragma unroll
        for (int j = 0; j < NT; ++j)
            #pragma unroll
            for (int r = 0; r < 4; ++r) {
                int row = m0 + wm * WM + i * 16 + lq * 4 + r;
                if (row < M) {
                    int col = wn * WN + j * 16 + lr;
                    Out[(size_t)row * BN + col] = (__bf16)acc[i][j][r];
                }
            }
}

// --------------------------- aggregation kernels ---------------------------
// EXACT R3 serial per-lane structure (verified absmax 0.03125).
// Wave-per-node: lane l reads csr row element l (CAP==64), coefs computed
// per-lane, broadcast via __shfl. Serial edge order j=0..n_e-1.

// HID=128: lane handles features {2l, 2l+1} as packed bf16x2 (uint).
__global__ __launch_bounds__(256) void agg_relu_w(const uint* __restrict__ Hin,
                                                  const float* __restrict__ inv,
                                                  const int* __restrict__ cnt,
                                                  const int* __restrict__ csr_pad,
                                                  const float* __restrict__ bias,
                                                  uint* __restrict__ Hout) {
    const int wid = threadIdx.x >> 6, lane = threadIdx.x & 63;
    const int v = blockIdx.x * 4 + wid;
    if (v >= NN) return;
    const float isv = inv[v];
    const int n_e = min(cnt[v], CAP);
    int sidx = 0;
    if (lane < n_e) sidx = csr_pad[(size_t)v * CAP + lane];   // predicated fetch
    float c = inv[sidx] * isv;
    uint u = Hin[(size_t)v * 64 + lane];
    float ax = bf_lo(u) * isv * isv;
    float ay = bf_hi(u) * isv * isv;
    int j = 0;
    for (; j + 3 < n_e; j += 4) {
        int s0 = __shfl(sidx, j), s1 = __shfl(sidx, j + 1);
        int s2 = __shfl(sidx, j + 2), s3 = __shfl(sidx, j + 3);
        float c0 = __shfl(c, j), c1 = __shfl(c, j + 1);
        float c2 = __shfl(c, j + 2), c3 = __shfl(c, j + 3);
        uint h0 = Hin[(size_t)s0 * 64 + lane];
        uint h1 = Hin[(size_t)s1 * 64 + lane];
        uint h2 = Hin[(size_t)s2 * 64 + lane];
        uint h3 = Hin[(size_t)s3 * 64 + lane];
        ax += c0 * bf_lo(h0); ay += c0 * bf_hi(h0);
        ax += c1 * bf_lo(h1); ay += c1 * bf_hi(h1);
        ax += c2 * bf_lo(h2); ay += c2 * bf_hi(h2);
        ax += c3 * bf_lo(h3); ay += c3 * bf_hi(h3);
    }
    for (; j < n_e; ++j) {
        int s0 = __shfl(sidx, j);
        float c0 = __shfl(c, j);
        uint h0 = Hin[(size_t)s0 * 64 + lane];
        ax += c0 * bf_lo(h0); ay += c0 * bf_hi(h0);
    }
    float ox = fmaxf(ax + bias[2 * lane], 0.f);
    float oy = fmaxf(ay + bias[2 * lane + 1], 0.f);
    __bf16 blo = (__bf16)ox, bhi = (__bf16)oy;
    uint res = (uint)*(ushort*)&blo | ((uint)*(ushort*)&bhi << 16);
    Hout[(size_t)v * 64 + lane] = res;
}

// CLS=64: lane == class. Serial edge order; bf16 logit rows (R3-verified).
__global__ __launch_bounds__(256) void agg_softmax_w(const ushort* __restrict__ Hin,
                                                     const float* __restrict__ inv,
                                                     const int* __restrict__ cnt,
                                                     const int* __restrict__ csr_pad,
                                                     const float* __restrict__ bias,
                                                     float* __restrict__ out) {
    const int wid = threadIdx.x >> 6, lane = threadIdx.x & 63;
    const int v = blockIdx.x * 4 + wid;
    if (v >= NN) return;
    const float isv = inv[v];
    const int n_e = min(cnt[v], CAP);
    int sidx = 0;
    if (lane < n_e) sidx = csr_pad[(size_t)v * CAP + lane];   // predicated fetch
    float c = inv[sidx] * isv;
    uint u = (uint)Hin[(size_t)v * 64 + lane];
    float acc = __uint_as_float(u << 16) * isv * isv;
    int j = 0;
    for (; j + 3 < n_e; j += 4) {
        int s0 = __shfl(sidx, j), s1 = __shfl(sidx, j + 1);
        int s2 = __shfl(sidx, j + 2), s3 = __shfl(sidx, j + 3);
        float c0 = __shfl(c, j), c1 = __shfl(c, j + 1);
        float c2 = __shfl(c, j + 2), c3 = __shfl(c, j + 3);
        uint h0 = (uint)Hin[(size_t)s0 * 64 + lane];
        uint h1 = (uint)Hin[(size_t)s1 * 64 + lane];
        uint h2 = (uint)Hin[(size_t)s2 * 64 + lane];
        uint h3 = (uint)Hin[(size_t)s3 * 64 + lane];
        acc += c0 * __uint_as_float(h0 << 16);
        acc += c1 * __uint_as_float(h1 << 16);
        acc += c2 * __uint_as_float(h2 << 16);
        acc += c3 * __uint_as_float(h3 << 16);
    }
    for (; j < n_e; ++j) {
        int s0 = __shfl(sidx, j);
        float c0 = __shfl(c, j);
        uint h0 = (uint)Hin[(size_t)s0 * 64 + lane];
        acc += c0 * __uint_as_float(h0 << 16);
    }
    float o = acc + bias[lane];
    float m = o;
    #pragma unroll
    for (int off = 32; off >= 1; off >>= 1) m = fmaxf(m, __shfl_xor(m, off, 64));
    float e = __expf(o - m);
    float s = e;
    #pragma unroll
    for (int off = 32; off >= 1; off >>= 1) s += __shfl_xor(s, off, 64);
    out[(size_t)v * CLS + lane] = (o - m) - __logf(s);
}

// ------------------------------- launcher ----------------------------------

extern "C" void kernel_launch(void* const* d_in, const int* in_sizes, int n_in,
                              void* d_out, int out_size, void* d_ws, size_t ws_size,
                              hipStream_t stream) {
    const float* x   = (const float*)d_in[0];
    const int*   src = (const int*)d_in[1];
    const int*   dst = (const int*)d_in[2];
    const float* W1  = (const float*)d_in[3];
    const float* b1  = (const float*)d_in[4];
    const float* W2  = (const float*)d_in[5];
    const float* b2  = (const float*)d_in[6];
    float* out = (float*)d_out;

    char* p = (char*)d_ws;
    size_t off = 0;
    auto alloc = [&](size_t bytes) {
        off = (off + 255) & ~(size_t)255;
        char* r = p + off;
        off += bytes;
        return r;
    };
    int*    cnt     = (int*)alloc(NN * 4);
    float*  inv     = (float*)alloc(NN * 4);
    int*    boff    = (int*)alloc((size_t)NBUCK * NBLK * 4);        // 0.6 MB
    int*    bcnt    = (int*)alloc((size_t)NBUCK * NBLK * 4);        // 0.6 MB
    uint*   bbuf    = (uint*)alloc((size_t)NBLK * EPB * 4);         // 6.4 MB
    int*    csr_pad = (int*)alloc((size_t)(NN + 256) * CAP * 4);    // 25.7 MB (+slack for dense copy)
    __bf16* W1t     = (__bf16*)alloc((size_t)F_IN * HID * 2);
    __bf16* W2t     = (__bf16*)alloc((size_t)HID * CLS * 2);
    __bf16* P1b     = (__bf16*)alloc((size_t)NN * HID * 2);
    __bf16* H1b     = (__bf16*)alloc((size_t)NN * HID * 2);
    __bf16* P2b     = (__bf16*)alloc((size_t)NN * CLS * 2);         // 12.8 MB bf16 logits

    cvt_weights<<<(F_IN * HID + 255) / 256, 256, 0, stream>>>(W1, W2, W1t, W2t);

    // pass1a binning (391 blocks) + GEMM1 X@W1 (782 blocks), fused
    const int MB1 = (NN + 127) / 128;    // 782
    fused_bin_gemm1<128, HID, 64, F_IN><<<NBLK + MB1, 256, 0, stream>>>(
        x, W1t, P1b, NN, src, dst, boff, bcnt, bbuf);

    build_rows<<<NBUCK, 256, 0, stream>>>(bbuf, boff, bcnt, cnt, inv, csr_pad);

    agg_relu_w<<<(NN + 3) / 4, 256, 0, stream>>>((const uint*)P1b, inv, cnt, csr_pad, b1, (uint*)H1b);

    gemm_bt<128, CLS, 128, HID><<<MB1, 256, 0, stream>>>(H1b, W2t, P2b, NN);

    agg_softmax_w<<<(NN + 3) / 4, 256, 0, stream>>>((const ushort*)P2b, inv, cnt, csr_pad, b2, out);
}